// Round 1
// baseline (1009.607 us; speedup 1.0000x reference)
//
#include <hip/hip_runtime.h>

#define NN 100000
#define EE 1250000
#define DD 64
#define GG 256
#define SCAN_CHUNK 1024
#define NB_SCAN ((NN + SCAN_CHUNK - 1) / SCAN_CHUNK)   // 98

static __device__ __forceinline__ float relu_f(float x) { return fmaxf(x, 0.0f); }

// ---------------- CSR build (counting sort by dst) ----------------

__global__ void hist_kernel(const int* __restrict__ dst, int* __restrict__ deg, int E) {
    int e = blockIdx.x * blockDim.x + threadIdx.x;
    if (e < E) atomicAdd(&deg[dst[e]], 1);
}

// block-local exclusive scan over 1024-element chunks
__global__ void scanA_kernel(const int* __restrict__ deg, int* __restrict__ off,
                             int* __restrict__ partials, int n) {
    __shared__ int tmp[256];
    int t = threadIdx.x;
    int base = blockIdx.x * SCAN_CHUNK + t * 4;
    int v0 = (base + 0 < n) ? deg[base + 0] : 0;
    int v1 = (base + 1 < n) ? deg[base + 1] : 0;
    int v2 = (base + 2 < n) ? deg[base + 2] : 0;
    int v3 = (base + 3 < n) ? deg[base + 3] : 0;
    int s4 = v0 + v1 + v2 + v3;
    tmp[t] = s4;
    __syncthreads();
    for (int d = 1; d < 256; d <<= 1) {
        int v = (t >= d) ? tmp[t - d] : 0;
        __syncthreads();
        tmp[t] += v;
        __syncthreads();
    }
    int run = tmp[t] - s4;  // exclusive within block
    if (base + 0 < n) off[base + 0] = run; run += v0;
    if (base + 1 < n) off[base + 1] = run; run += v1;
    if (base + 2 < n) off[base + 2] = run; run += v2;
    if (base + 3 < n) off[base + 3] = run;
    if (t == 255) partials[blockIdx.x] = tmp[255];
}

__global__ void scanB_kernel(const int* __restrict__ partials, int* __restrict__ pref, int nb) {
    __shared__ int tmp[128];
    int t = threadIdx.x;
    int v = (t < nb) ? partials[t] : 0;
    tmp[t] = v;
    __syncthreads();
    for (int d = 1; d < 128; d <<= 1) {
        int u = (t >= d) ? tmp[t - d] : 0;
        __syncthreads();
        tmp[t] += u;
        __syncthreads();
    }
    if (t < nb) pref[t] = tmp[t] - v;
}

__global__ void scanC_kernel(int* __restrict__ off, int* __restrict__ cursor,
                             const int* __restrict__ pref, int n) {
    int i = blockIdx.x * blockDim.x + threadIdx.x;
    if (i < n) {
        int o = off[i] + pref[i >> 10];
        off[i] = o;
        cursor[i] = o;
    }
}

__global__ void scatter_kernel(const int* __restrict__ ei, int* __restrict__ cursor,
                               int* __restrict__ srcs, int E) {
    int e = blockIdx.x * blockDim.x + threadIdx.x;
    if (e < E) {
        int s = ei[e];        // src
        int d = ei[E + e];    // dst
        int pos = atomicAdd(&cursor[d], 1);
        srcs[pos] = s;
    }
}

// ---------------- per-layer: aggregation (wave per node) ----------------
// u[i] = x[i] + sum_{j in-neighbors} x[src_j]
__global__ __launch_bounds__(256) void agg_kernel(
    const float* __restrict__ x, float* __restrict__ u,
    const int* __restrict__ off, const int* __restrict__ deg,
    const int* __restrict__ srcs, int n) {
    int node = blockIdx.x * 4 + (threadIdx.x >> 6);
    int lane = threadIdx.x & 63;
    if (node >= n) return;
    int o = off[node];
    int dc = deg[node];
    float acc = x[(size_t)node * DD + lane];
    for (int j = 0; j < dc; j++) {
        int s = srcs[o + j];               // wave-uniform load
        acc += x[(size_t)s * DD + lane];   // coalesced 256B row read
    }
    u[(size_t)node * DD + lane] = acc;
}

// ---------------- per-layer: fused MLP + outer ReLU (+ BN) ----------------
// h = [bn](relu( relu(u@wa+ba) @ wb + bb ))
template <bool HAS_BN>
__global__ __launch_bounds__(256) void mlp_kernel(
    const float* __restrict__ u, float* __restrict__ h,
    const float* __restrict__ wa, const float* __restrict__ ba,
    const float* __restrict__ wb, const float* __restrict__ bb,
    const float* __restrict__ bng, const float* __restrict__ bnb,
    const float* __restrict__ bnm, const float* __restrict__ bnv, int n) {
    int i = blockIdx.x * blockDim.x + threadIdx.x;
    if (i >= n) return;

    float uu[DD];
    const float4* up = (const float4*)(u + (size_t)i * DD);
#pragma unroll
    for (int q = 0; q < DD / 4; q++) {
        float4 v = up[q];
        uu[4 * q + 0] = v.x; uu[4 * q + 1] = v.y;
        uu[4 * q + 2] = v.z; uu[4 * q + 3] = v.w;
    }

    float acc[DD];
#pragma unroll
    for (int o = 0; o < DD; o++) acc[o] = bb[o];

#pragma unroll 1
    for (int j = 0; j < DD; j++) {   // j wave-uniform -> weight loads go scalar
        float a = ba[j];
#pragma unroll
        for (int k = 0; k < DD; k++) a = fmaf(uu[k], wa[k * DD + j], a);
        a = relu_f(a);
#pragma unroll
        for (int o = 0; o < DD; o++) acc[o] = fmaf(a, wb[j * DD + o], acc[o]);
    }

    float4* hp = (float4*)(h + (size_t)i * DD);
#pragma unroll
    for (int q = 0; q < DD / 4; q++) {
        float r[4];
#pragma unroll
        for (int c = 0; c < 4; c++) {
            int o = 4 * q + c;
            float v = relu_f(acc[o]);
            if (HAS_BN) {
                float sc = bng[o] * rsqrtf(bnv[o] + 1e-5f);
                float sh = bnb[o] - bnm[o] * sc;
                v = fmaf(v, sc, sh);
            }
            r[c] = v;
        }
        float4 v4; v4.x = r[0]; v4.y = r[1]; v4.z = r[2]; v4.w = r[3];
        hp[q] = v4;
    }
}

// ---------------- pooling (wave per node, per-graph atomics) ----------------
__global__ __launch_bounds__(256) void pool_kernel(
    const float* __restrict__ h, const int* __restrict__ batch,
    float* __restrict__ psum, int* __restrict__ pmax, int* __restrict__ pcnt, int n) {
    int node = blockIdx.x * 4 + (threadIdx.x >> 6);
    int lane = threadIdx.x & 63;
    if (node >= n) return;
    int g = batch[node];
    float v = h[(size_t)node * DD + lane];
    atomicAdd(&psum[g * DD + lane], v);
    atomicMax(&pmax[g * DD + lane], __float_as_int(v));  // v >= 0, int order == float order
    if (lane == 0) atomicAdd(&pcnt[g], 1);
}

// ---------------- head: MLP + log_softmax, one 64-thread block per graph ----
__global__ __launch_bounds__(64) void head_kernel(
    const float* __restrict__ psum, const int* __restrict__ pmax,
    const int* __restrict__ pcnt,
    const float* __restrict__ wp1, const float* __restrict__ bp1,
    const float* __restrict__ wp2, const float* __restrict__ bp2,
    float* __restrict__ out) {
    __shared__ float gx[2 * DD];
    int g = blockIdx.x;
    int lane = threadIdx.x;
    float cntf = fmaxf((float)pcnt[g], 1.0f);
    gx[lane] = psum[g * DD + lane] / cntf;
    gx[DD + lane] = __int_as_float(pmax[g * DD + lane]);
    __syncthreads();
    float t = bp1[lane];
    for (int k = 0; k < 2 * DD; k++) t = fmaf(gx[k], wp1[k * DD + lane], t);
    float p0 = t * wp2[lane * 2 + 0];
    float p1 = t * wp2[lane * 2 + 1];
    for (int o = 32; o > 0; o >>= 1) {
        p0 += __shfl_down(p0, o);
        p1 += __shfl_down(p1, o);
    }
    if (lane == 0) {
        p0 += bp2[0];
        p1 += bp2[1];
        float m = fmaxf(p0, p1);
        float lse = m + logf(expf(p0 - m) + expf(p1 - m));
        out[g * 2 + 0] = p0 - lse;
        out[g * 2 + 1] = p1 - lse;
    }
}

// ---------------- launch ----------------
extern "C" void kernel_launch(void* const* d_in, const int* in_sizes, int n_in,
                              void* d_out, int out_size, void* d_ws, size_t ws_size,
                              hipStream_t stream) {
    const float* x     = (const float*)d_in[0];
    const int*   ei    = (const int*)d_in[1];
    const int*   batch = (const int*)d_in[2];
    const float* w0a = (const float*)d_in[3];  const float* b0a = (const float*)d_in[4];
    const float* w0b = (const float*)d_in[5];  const float* b0b = (const float*)d_in[6];
    const float* w1a = (const float*)d_in[7];  const float* b1a = (const float*)d_in[8];
    const float* w1b = (const float*)d_in[9];  const float* b1b = (const float*)d_in[10];
    const float* w2a = (const float*)d_in[11]; const float* b2a = (const float*)d_in[12];
    const float* w2b = (const float*)d_in[13]; const float* b2b = (const float*)d_in[14];
    const float* bn0g = (const float*)d_in[15]; const float* bn0b = (const float*)d_in[16];
    const float* bn0m = (const float*)d_in[17]; const float* bn0v = (const float*)d_in[18];
    const float* bn1g = (const float*)d_in[19]; const float* bn1b = (const float*)d_in[20];
    const float* bn1m = (const float*)d_in[21]; const float* bn1v = (const float*)d_in[22];
    const float* wp1 = (const float*)d_in[23]; const float* bp1 = (const float*)d_in[24];
    const float* wp2 = (const float*)d_in[25]; const float* bp2 = (const float*)d_in[26];
    float* out = (float*)d_out;

    // workspace carve (all 256B aligned)
    char* p = (char*)d_ws;
    auto take = [&](size_t bytes) {
        char* r = p;
        p += (bytes + 255) & ~(size_t)255;
        return r;
    };
    int* deg     = (int*)take(NN * sizeof(int));
    int* off     = (int*)take(NN * sizeof(int));
    int* cursor  = (int*)take(NN * sizeof(int));
    int* partials= (int*)take(128 * sizeof(int));
    int* pref    = (int*)take(128 * sizeof(int));
    int* srcs    = (int*)take(EE * sizeof(int));
    float* bufA  = (float*)take((size_t)NN * DD * sizeof(float));
    float* bufB  = (float*)take((size_t)NN * DD * sizeof(float));
    float* psum  = (float*)take(GG * DD * sizeof(float));
    int* pmax    = (int*)take(GG * DD * sizeof(int));
    int* pcnt    = (int*)take(GG * sizeof(int));

    // CSR build
    hipMemsetAsync(deg, 0, NN * sizeof(int), stream);
    hist_kernel<<<(EE + 255) / 256, 256, 0, stream>>>(ei + EE, deg, EE);
    scanA_kernel<<<NB_SCAN, 256, 0, stream>>>(deg, off, partials, NN);
    scanB_kernel<<<1, 128, 0, stream>>>(partials, pref, NB_SCAN);
    scanC_kernel<<<(NN + 255) / 256, 256, 0, stream>>>(off, cursor, pref, NN);
    scatter_kernel<<<(EE + 255) / 256, 256, 0, stream>>>(ei, cursor, srcs, EE);

    int agg_grid = (NN + 3) / 4;
    int mlp_grid = (NN + 255) / 256;

    // layer 0: x -> bufA (u) -> bufA (h, bn0)
    agg_kernel<<<agg_grid, 256, 0, stream>>>(x, bufA, off, deg, srcs, NN);
    mlp_kernel<true><<<mlp_grid, 256, 0, stream>>>(bufA, bufA, w0a, b0a, w0b, b0b,
                                                   bn0g, bn0b, bn0m, bn0v, NN);
    // layer 1: bufA -> bufB -> bufB (bn1)
    agg_kernel<<<agg_grid, 256, 0, stream>>>(bufA, bufB, off, deg, srcs, NN);
    mlp_kernel<true><<<mlp_grid, 256, 0, stream>>>(bufB, bufB, w1a, b1a, w1b, b1b,
                                                   bn1g, bn1b, bn1m, bn1v, NN);
    // layer 2: bufB -> bufA -> bufA (no bn)
    agg_kernel<<<agg_grid, 256, 0, stream>>>(bufB, bufA, off, deg, srcs, NN);
    mlp_kernel<false><<<mlp_grid, 256, 0, stream>>>(bufA, bufA, w2a, b2a, w2b, b2b,
                                                    nullptr, nullptr, nullptr, nullptr, NN);

    // pooling
    hipMemsetAsync(psum, 0, GG * DD * sizeof(float), stream);
    hipMemsetAsync(pmax, 0, GG * DD * sizeof(int), stream);
    hipMemsetAsync(pcnt, 0, GG * sizeof(int), stream);
    pool_kernel<<<agg_grid, 256, 0, stream>>>(bufA, batch, psum, pmax, pcnt, NN);

    // head
    head_kernel<<<GG, 64, 0, stream>>>(psum, pmax, pcnt, wp1, bp1, wp2, bp2, out);
}

// Round 2
// 721.895 us; speedup vs baseline: 1.3986x; 1.3986x over previous
//
#include <hip/hip_runtime.h>

#define NN 100000
#define EE 1250000
#define DD 64
#define GG 256
#define SCAN_CHUNK 1024
#define NB_SCAN ((NN + SCAN_CHUNK - 1) / SCAN_CHUNK)   // 98

static __device__ __forceinline__ float relu_f(float x) { return fmaxf(x, 0.0f); }

// ---------------- CSR build (counting sort by dst) ----------------

__global__ void hist_kernel(const int* __restrict__ dst, int* __restrict__ deg, int E) {
    int e = blockIdx.x * blockDim.x + threadIdx.x;
    if (e < E) atomicAdd(&deg[dst[e]], 1);
}

__global__ void scanA_kernel(const int* __restrict__ deg, int* __restrict__ off,
                             int* __restrict__ partials, int n) {
    __shared__ int tmp[256];
    int t = threadIdx.x;
    int base = blockIdx.x * SCAN_CHUNK + t * 4;
    int v0 = (base + 0 < n) ? deg[base + 0] : 0;
    int v1 = (base + 1 < n) ? deg[base + 1] : 0;
    int v2 = (base + 2 < n) ? deg[base + 2] : 0;
    int v3 = (base + 3 < n) ? deg[base + 3] : 0;
    int s4 = v0 + v1 + v2 + v3;
    tmp[t] = s4;
    __syncthreads();
    for (int d = 1; d < 256; d <<= 1) {
        int v = (t >= d) ? tmp[t - d] : 0;
        __syncthreads();
        tmp[t] += v;
        __syncthreads();
    }
    int run = tmp[t] - s4;  // exclusive within block
    if (base + 0 < n) off[base + 0] = run; run += v0;
    if (base + 1 < n) off[base + 1] = run; run += v1;
    if (base + 2 < n) off[base + 2] = run; run += v2;
    if (base + 3 < n) off[base + 3] = run;
    if (t == 255) partials[blockIdx.x] = tmp[255];
}

__global__ void scanB_kernel(const int* __restrict__ partials, int* __restrict__ pref, int nb) {
    __shared__ int tmp[128];
    int t = threadIdx.x;
    int v = (t < nb) ? partials[t] : 0;
    tmp[t] = v;
    __syncthreads();
    for (int d = 1; d < 128; d <<= 1) {
        int u = (t >= d) ? tmp[t - d] : 0;
        __syncthreads();
        tmp[t] += u;
        __syncthreads();
    }
    if (t < nb) pref[t] = tmp[t] - v;
}

__global__ void scanC_kernel(int* __restrict__ off, int* __restrict__ cursor,
                             const int* __restrict__ pref, int n) {
    int i = blockIdx.x * blockDim.x + threadIdx.x;
    if (i < n) {
        int o = off[i] + pref[i >> 10];
        off[i] = o;
        cursor[i] = o;
    }
}

__global__ void scatter_kernel(const int* __restrict__ ei, int* __restrict__ cursor,
                               int* __restrict__ srcs, int E) {
    int e = blockIdx.x * blockDim.x + threadIdx.x;
    if (e < E) {
        int s = ei[e];        // src
        int d = ei[E + e];    // dst
        int pos = atomicAdd(&cursor[d], 1);
        srcs[pos] = s;
    }
}

// graph boundaries from sorted batch: gstart[g] = first node with batch >= g
__global__ void bounds_kernel(const int* __restrict__ batch, int* __restrict__ gstart, int n) {
    int i = blockIdx.x * blockDim.x + threadIdx.x;
    if (i >= n) return;
    int b = batch[i];
    int prev = (i == 0) ? -1 : batch[i - 1];
    for (int g = prev + 1; g <= b; g++) gstart[g] = i;
    if (i == n - 1) {
        for (int g = b + 1; g <= GG; g++) gstart[g] = n;
    }
}

// ---------------- per-layer: aggregation (wave per node) ----------------
__global__ __launch_bounds__(256) void agg_kernel(
    const float* __restrict__ x, float* __restrict__ u,
    const int* __restrict__ off, const int* __restrict__ deg,
    const int* __restrict__ srcs, int n) {
    int node = blockIdx.x * 4 + (threadIdx.x >> 6);
    int lane = threadIdx.x & 63;
    if (node >= n) return;
    int o = off[node];
    int dc = deg[node];
    float acc = x[(size_t)node * DD + lane];
    for (int j = 0; j < dc; j++) {
        int s = srcs[o + j];               // wave-uniform load
        acc += x[(size_t)s * DD + lane];   // coalesced 256B row read
    }
    u[(size_t)node * DD + lane] = acc;
}

// ---------------- per-layer: fused MLP + outer ReLU (+ BN) ----------------
template <bool HAS_BN>
__global__ __launch_bounds__(256) void mlp_kernel(
    const float* __restrict__ u, float* __restrict__ h,
    const float* __restrict__ wa, const float* __restrict__ ba,
    const float* __restrict__ wb, const float* __restrict__ bb,
    const float* __restrict__ bng, const float* __restrict__ bnb,
    const float* __restrict__ bnm, const float* __restrict__ bnv, int n) {
    int i = blockIdx.x * blockDim.x + threadIdx.x;
    if (i >= n) return;

    float uu[DD];
    const float4* up = (const float4*)(u + (size_t)i * DD);
#pragma unroll
    for (int q = 0; q < DD / 4; q++) {
        float4 v = up[q];
        uu[4 * q + 0] = v.x; uu[4 * q + 1] = v.y;
        uu[4 * q + 2] = v.z; uu[4 * q + 3] = v.w;
    }

    float acc[DD];
#pragma unroll
    for (int o = 0; o < DD; o++) acc[o] = bb[o];

#pragma unroll 1
    for (int j = 0; j < DD; j++) {   // j wave-uniform -> weight loads go scalar
        float a = ba[j];
#pragma unroll
        for (int k = 0; k < DD; k++) a = fmaf(uu[k], wa[k * DD + j], a);
        a = relu_f(a);
#pragma unroll
        for (int o = 0; o < DD; o++) acc[o] = fmaf(a, wb[j * DD + o], acc[o]);
    }

    float4* hp = (float4*)(h + (size_t)i * DD);
#pragma unroll
    for (int q = 0; q < DD / 4; q++) {
        float r[4];
#pragma unroll
        for (int c = 0; c < 4; c++) {
            int o = 4 * q + c;
            float v = relu_f(acc[o]);
            if (HAS_BN) {
                float sc = bng[o] * rsqrtf(bnv[o] + 1e-5f);
                float sh = bnb[o] - bnm[o] * sc;
                v = fmaf(v, sc, sh);
            }
            r[c] = v;
        }
        float4 v4; v4.x = r[0]; v4.y = r[1]; v4.z = r[2]; v4.w = r[3];
        hp[q] = v4;
    }
}

// ---------------- pooling: one block per graph, zero atomics ----------------
// batch sorted -> graph g owns nodes [gstart[g], gstart[g+1])
__global__ __launch_bounds__(256) void pool_kernel(
    const float* __restrict__ h, const int* __restrict__ gstart,
    float* __restrict__ pmean, float* __restrict__ pmax) {
    __shared__ float ssum[4][DD];
    __shared__ float smax[4][DD];
    int g = blockIdx.x;
    int lane = threadIdx.x & 63;
    int wave = threadIdx.x >> 6;
    int s = gstart[g], e = gstart[g + 1];
    float sum = 0.0f, mx = 0.0f;  // h >= 0 (post-ReLU); 0 matches empty-graph guard
    for (int i = s + wave; i < e; i += 4) {
        float v = h[(size_t)i * DD + lane];
        sum += v;
        mx = fmaxf(mx, v);
    }
    ssum[wave][lane] = sum;
    smax[wave][lane] = mx;
    __syncthreads();
    if (wave == 0) {
        sum = ssum[0][lane] + ssum[1][lane] + ssum[2][lane] + ssum[3][lane];
        mx = fmaxf(fmaxf(smax[0][lane], smax[1][lane]),
                   fmaxf(smax[2][lane], smax[3][lane]));
        float cnt = fmaxf((float)(e - s), 1.0f);
        pmean[g * DD + lane] = sum / cnt;
        pmax[g * DD + lane] = mx;
    }
}

// ---------------- head: MLP + log_softmax, one 64-thread block per graph ----
__global__ __launch_bounds__(64) void head_kernel(
    const float* __restrict__ pmean, const float* __restrict__ pmax,
    const float* __restrict__ wp1, const float* __restrict__ bp1,
    const float* __restrict__ wp2, const float* __restrict__ bp2,
    float* __restrict__ out) {
    __shared__ float gx[2 * DD];
    int g = blockIdx.x;
    int lane = threadIdx.x;
    gx[lane] = pmean[g * DD + lane];
    gx[DD + lane] = pmax[g * DD + lane];
    __syncthreads();
    float t = bp1[lane];
    for (int k = 0; k < 2 * DD; k++) t = fmaf(gx[k], wp1[k * DD + lane], t);
    float p0 = t * wp2[lane * 2 + 0];
    float p1 = t * wp2[lane * 2 + 1];
    for (int o = 32; o > 0; o >>= 1) {
        p0 += __shfl_down(p0, o);
        p1 += __shfl_down(p1, o);
    }
    if (lane == 0) {
        p0 += bp2[0];
        p1 += bp2[1];
        float m = fmaxf(p0, p1);
        float lse = m + logf(expf(p0 - m) + expf(p1 - m));
        out[g * 2 + 0] = p0 - lse;
        out[g * 2 + 1] = p1 - lse;
    }
}

// ---------------- launch ----------------
extern "C" void kernel_launch(void* const* d_in, const int* in_sizes, int n_in,
                              void* d_out, int out_size, void* d_ws, size_t ws_size,
                              hipStream_t stream) {
    const float* x     = (const float*)d_in[0];
    const int*   ei    = (const int*)d_in[1];
    const int*   batch = (const int*)d_in[2];
    const float* w0a = (const float*)d_in[3];  const float* b0a = (const float*)d_in[4];
    const float* w0b = (const float*)d_in[5];  const float* b0b = (const float*)d_in[6];
    const float* w1a = (const float*)d_in[7];  const float* b1a = (const float*)d_in[8];
    const float* w1b = (const float*)d_in[9];  const float* b1b = (const float*)d_in[10];
    const float* w2a = (const float*)d_in[11]; const float* b2a = (const float*)d_in[12];
    const float* w2b = (const float*)d_in[13]; const float* b2b = (const float*)d_in[14];
    const float* bn0g = (const float*)d_in[15]; const float* bn0b = (const float*)d_in[16];
    const float* bn0m = (const float*)d_in[17]; const float* bn0v = (const float*)d_in[18];
    const float* bn1g = (const float*)d_in[19]; const float* bn1b = (const float*)d_in[20];
    const float* bn1m = (const float*)d_in[21]; const float* bn1v = (const float*)d_in[22];
    const float* wp1 = (const float*)d_in[23]; const float* bp1 = (const float*)d_in[24];
    const float* wp2 = (const float*)d_in[25]; const float* bp2 = (const float*)d_in[26];
    float* out = (float*)d_out;

    char* p = (char*)d_ws;
    auto take = [&](size_t bytes) {
        char* r = p;
        p += (bytes + 255) & ~(size_t)255;
        return r;
    };
    int* deg     = (int*)take(NN * sizeof(int));
    int* off     = (int*)take(NN * sizeof(int));
    int* cursor  = (int*)take(NN * sizeof(int));
    int* partials= (int*)take(128 * sizeof(int));
    int* pref    = (int*)take(128 * sizeof(int));
    int* srcs    = (int*)take(EE * sizeof(int));
    int* gstart  = (int*)take((GG + 1) * sizeof(int));
    float* bufA  = (float*)take((size_t)NN * DD * sizeof(float));
    float* bufB  = (float*)take((size_t)NN * DD * sizeof(float));
    float* pmean = (float*)take(GG * DD * sizeof(float));
    float* pmax  = (float*)take(GG * DD * sizeof(float));

    // CSR build + graph bounds
    hipMemsetAsync(deg, 0, NN * sizeof(int), stream);
    hist_kernel<<<(EE + 255) / 256, 256, 0, stream>>>(ei + EE, deg, EE);
    scanA_kernel<<<NB_SCAN, 256, 0, stream>>>(deg, off, partials, NN);
    scanB_kernel<<<1, 128, 0, stream>>>(partials, pref, NB_SCAN);
    scanC_kernel<<<(NN + 255) / 256, 256, 0, stream>>>(off, cursor, pref, NN);
    scatter_kernel<<<(EE + 255) / 256, 256, 0, stream>>>(ei, cursor, srcs, EE);
    bounds_kernel<<<(NN + 255) / 256, 256, 0, stream>>>(batch, gstart, NN);

    int agg_grid = (NN + 3) / 4;
    int mlp_grid = (NN + 255) / 256;

    // layer 0
    agg_kernel<<<agg_grid, 256, 0, stream>>>(x, bufA, off, deg, srcs, NN);
    mlp_kernel<true><<<mlp_grid, 256, 0, stream>>>(bufA, bufA, w0a, b0a, w0b, b0b,
                                                   bn0g, bn0b, bn0m, bn0v, NN);
    // layer 1
    agg_kernel<<<agg_grid, 256, 0, stream>>>(bufA, bufB, off, deg, srcs, NN);
    mlp_kernel<true><<<mlp_grid, 256, 0, stream>>>(bufB, bufB, w1a, b1a, w1b, b1b,
                                                   bn1g, bn1b, bn1m, bn1v, NN);
    // layer 2
    agg_kernel<<<agg_grid, 256, 0, stream>>>(bufB, bufA, off, deg, srcs, NN);
    mlp_kernel<false><<<mlp_grid, 256, 0, stream>>>(bufA, bufA, w2a, b2a, w2b, b2b,
                                                    nullptr, nullptr, nullptr, nullptr, NN);

    // pooling (no atomics) + head
    pool_kernel<<<GG, 256, 0, stream>>>(bufA, gstart, pmean, pmax);
    head_kernel<<<GG, 64, 0, stream>>>(pmean, pmax, wp1, bp1, wp2, bp2, out);
}

// Round 3
// 505.343 us; speedup vs baseline: 1.9979x; 1.4285x over previous
//
#include <hip/hip_runtime.h>
#include <hip/hip_bf16.h>

#define NN 100000
#define EE 1250000
#define DD 64
#define GG 256
#define SCAN_CHUNK 1024
#define NB_SCAN ((NN + SCAN_CHUNK - 1) / SCAN_CHUNK)   // 98

static __device__ __forceinline__ float relu_f(float x) { return fmaxf(x, 0.0f); }

static __device__ __forceinline__ float b2f(ushort u) {
    return __uint_as_float(((unsigned int)u) << 16);
}
static __device__ __forceinline__ ushort f2b(float f) {
    __hip_bfloat16 h = __float2bfloat16(f);  // RNE
    return *(ushort*)&h;
}

// ---------------- CSR build (counting sort by dst) ----------------

__global__ void hist_kernel(const int* __restrict__ dst, int* __restrict__ deg, int E) {
    int e = blockIdx.x * blockDim.x + threadIdx.x;
    if (e < E) atomicAdd(&deg[dst[e]], 1);
}

__global__ void scanA_kernel(const int* __restrict__ deg, int* __restrict__ off,
                             int* __restrict__ partials, int n) {
    __shared__ int tmp[256];
    int t = threadIdx.x;
    int base = blockIdx.x * SCAN_CHUNK + t * 4;
    int v0 = (base + 0 < n) ? deg[base + 0] : 0;
    int v1 = (base + 1 < n) ? deg[base + 1] : 0;
    int v2 = (base + 2 < n) ? deg[base + 2] : 0;
    int v3 = (base + 3 < n) ? deg[base + 3] : 0;
    int s4 = v0 + v1 + v2 + v3;
    tmp[t] = s4;
    __syncthreads();
    for (int d = 1; d < 256; d <<= 1) {
        int v = (t >= d) ? tmp[t - d] : 0;
        __syncthreads();
        tmp[t] += v;
        __syncthreads();
    }
    int run = tmp[t] - s4;  // exclusive within block
    if (base + 0 < n) off[base + 0] = run; run += v0;
    if (base + 1 < n) off[base + 1] = run; run += v1;
    if (base + 2 < n) off[base + 2] = run; run += v2;
    if (base + 3 < n) off[base + 3] = run;
    if (t == 255) partials[blockIdx.x] = tmp[255];
}

__global__ void scanB_kernel(const int* __restrict__ partials, int* __restrict__ pref, int nb) {
    __shared__ int tmp[128];
    int t = threadIdx.x;
    int v = (t < nb) ? partials[t] : 0;
    tmp[t] = v;
    __syncthreads();
    for (int d = 1; d < 128; d <<= 1) {
        int u = (t >= d) ? tmp[t - d] : 0;
        __syncthreads();
        tmp[t] += u;
        __syncthreads();
    }
    if (t < nb) pref[t] = tmp[t] - v;
}

__global__ void scanC_kernel(int* __restrict__ off, int* __restrict__ cursor,
                             const int* __restrict__ pref, const int* __restrict__ deg, int n) {
    int i = blockIdx.x * blockDim.x + threadIdx.x;
    if (i < n) {
        int o = off[i] + pref[i >> 10];
        off[i] = o;
        cursor[i] = o;
        if (i == n - 1) off[n] = o + deg[i];
    }
}

__global__ void scatter_kernel(const int* __restrict__ ei, int* __restrict__ cursor,
                               int* __restrict__ srcs, int E) {
    int e = blockIdx.x * blockDim.x + threadIdx.x;
    if (e < E) {
        int s = ei[e];        // src
        int d = ei[E + e];    // dst
        int pos = atomicAdd(&cursor[d], 1);
        srcs[pos] = s;
    }
}

// graph boundaries from sorted batch
__global__ void bounds_kernel(const int* __restrict__ batch, int* __restrict__ gstart, int n) {
    int i = blockIdx.x * blockDim.x + threadIdx.x;
    if (i >= n) return;
    int b = batch[i];
    int prev = (i == 0) ? -1 : batch[i - 1];
    for (int g = prev + 1; g <= b; g++) gstart[g] = i;
    if (i == n - 1) {
        for (int g = b + 1; g <= GG; g++) gstart[g] = n;
    }
}

// fp32 -> bf16 cast of x (once)
__global__ __launch_bounds__(256) void cast_kernel(const float* __restrict__ x,
                                                   ushort* __restrict__ xb) {
    size_t i = ((size_t)blockIdx.x * blockDim.x + threadIdx.x) * 4;
    if (i >= (size_t)NN * DD) return;
    float4 v = *(const float4*)(x + i);
    ushort4 r;
    r.x = f2b(v.x); r.y = f2b(v.y); r.z = f2b(v.z); r.w = f2b(v.w);
    *(ushort4*)(xb + i) = r;
}

// ---------------- aggregation: wave per node, bf16 gather, 4-deep MLP ------
// u[i] = x[i] + sum_{j in-neighbors} x[src_j]   (fp32 accumulate, fp32 out)
__global__ __launch_bounds__(256) void agg_kernel(
    const ushort* __restrict__ xb, float* __restrict__ u,
    const int* __restrict__ off, const int* __restrict__ srcs, int n) {
    int node = blockIdx.x * 4 + (threadIdx.x >> 6);
    int lane = threadIdx.x & 63;
    if (node >= n) return;
    int o = off[node];
    int oe = off[node + 1];
    float a0 = b2f(xb[(size_t)node * DD + lane]);   // self
    float a1 = 0.0f, a2 = 0.0f, a3 = 0.0f;
    int j = o;
    for (; j + 4 <= oe; j += 4) {
        int s0 = srcs[j + 0];
        int s1 = srcs[j + 1];
        int s2 = srcs[j + 2];
        int s3 = srcs[j + 3];
        ushort v0 = xb[(size_t)s0 * DD + lane];     // 4 independent gathers in flight
        ushort v1 = xb[(size_t)s1 * DD + lane];
        ushort v2 = xb[(size_t)s2 * DD + lane];
        ushort v3 = xb[(size_t)s3 * DD + lane];
        a0 += b2f(v0); a1 += b2f(v1); a2 += b2f(v2); a3 += b2f(v3);
    }
    for (; j < oe; j++) a0 += b2f(xb[(size_t)srcs[j] * DD + lane]);
    u[(size_t)node * DD + lane] = (a0 + a1) + (a2 + a3);
}

// ---------------- per-layer: fused MLP + outer ReLU (+ BN), bf16 out -------
template <bool HAS_BN>
__global__ __launch_bounds__(256) void mlp_kernel(
    const float* __restrict__ u, ushort* __restrict__ h,
    const float* __restrict__ wa, const float* __restrict__ ba,
    const float* __restrict__ wb, const float* __restrict__ bb,
    const float* __restrict__ bng, const float* __restrict__ bnb,
    const float* __restrict__ bnm, const float* __restrict__ bnv, int n) {
    int i = blockIdx.x * blockDim.x + threadIdx.x;
    if (i >= n) return;

    float uu[DD];
    const float4* up = (const float4*)(u + (size_t)i * DD);
#pragma unroll
    for (int q = 0; q < DD / 4; q++) {
        float4 v = up[q];
        uu[4 * q + 0] = v.x; uu[4 * q + 1] = v.y;
        uu[4 * q + 2] = v.z; uu[4 * q + 3] = v.w;
    }

    float acc[DD];
#pragma unroll
    for (int o = 0; o < DD; o++) acc[o] = bb[o];

#pragma unroll 1
    for (int j = 0; j < DD; j++) {   // j wave-uniform -> weight loads go scalar
        float a = ba[j];
#pragma unroll
        for (int k = 0; k < DD; k++) a = fmaf(uu[k], wa[k * DD + j], a);
        a = relu_f(a);
#pragma unroll
        for (int o = 0; o < DD; o++) acc[o] = fmaf(a, wb[j * DD + o], acc[o]);
    }

    ushort4* hp = (ushort4*)(h + (size_t)i * DD);
#pragma unroll
    for (int q = 0; q < DD / 4; q++) {
        ushort4 r;
        float v[4];
#pragma unroll
        for (int c = 0; c < 4; c++) {
            int o = 4 * q + c;
            float t = relu_f(acc[o]);
            if (HAS_BN) {
                float sc = bng[o] * rsqrtf(bnv[o] + 1e-5f);
                float sh = bnb[o] - bnm[o] * sc;
                t = fmaf(t, sc, sh);
            }
            v[c] = t;
        }
        r.x = f2b(v[0]); r.y = f2b(v[1]); r.z = f2b(v[2]); r.w = f2b(v[3]);
        hp[q] = r;
    }
}

// ---------------- pooling: one block per graph, zero atomics ----------------
__global__ __launch_bounds__(256) void pool_kernel(
    const ushort* __restrict__ h, const int* __restrict__ gstart,
    float* __restrict__ pmean, float* __restrict__ pmax) {
    __shared__ float ssum[4][DD];
    __shared__ float smax[4][DD];
    int g = blockIdx.x;
    int lane = threadIdx.x & 63;
    int wave = threadIdx.x >> 6;
    int s = gstart[g], e = gstart[g + 1];
    float sum = 0.0f, mx = 0.0f;  // h >= 0 pre-BN... values may be negative post-BN!
    // NOTE: layer-2 output has no BN and is post-ReLU -> h >= 0, so 0 init is safe
    for (int i = s + wave; i < e; i += 4) {
        float v = b2f(h[(size_t)i * DD + lane]);
        sum += v;
        mx = fmaxf(mx, v);
    }
    ssum[wave][lane] = sum;
    smax[wave][lane] = mx;
    __syncthreads();
    if (wave == 0) {
        sum = ssum[0][lane] + ssum[1][lane] + ssum[2][lane] + ssum[3][lane];
        mx = fmaxf(fmaxf(smax[0][lane], smax[1][lane]),
                   fmaxf(smax[2][lane], smax[3][lane]));
        float cnt = fmaxf((float)(e - s), 1.0f);
        pmean[g * DD + lane] = sum / cnt;
        pmax[g * DD + lane] = mx;
    }
}

// ---------------- head: MLP + log_softmax, one 64-thread block per graph ----
__global__ __launch_bounds__(64) void head_kernel(
    const float* __restrict__ pmean, const float* __restrict__ pmax,
    const float* __restrict__ wp1, const float* __restrict__ bp1,
    const float* __restrict__ wp2, const float* __restrict__ bp2,
    float* __restrict__ out) {
    __shared__ float gx[2 * DD];
    int g = blockIdx.x;
    int lane = threadIdx.x;
    gx[lane] = pmean[g * DD + lane];
    gx[DD + lane] = pmax[g * DD + lane];
    __syncthreads();
    float t = bp1[lane];
    for (int k = 0; k < 2 * DD; k++) t = fmaf(gx[k], wp1[k * DD + lane], t);
    float p0 = t * wp2[lane * 2 + 0];
    float p1 = t * wp2[lane * 2 + 1];
    for (int o = 32; o > 0; o >>= 1) {
        p0 += __shfl_down(p0, o);
        p1 += __shfl_down(p1, o);
    }
    if (lane == 0) {
        p0 += bp2[0];
        p1 += bp2[1];
        float m = fmaxf(p0, p1);
        float lse = m + logf(expf(p0 - m) + expf(p1 - m));
        out[g * 2 + 0] = p0 - lse;
        out[g * 2 + 1] = p1 - lse;
    }
}

// ---------------- launch ----------------
extern "C" void kernel_launch(void* const* d_in, const int* in_sizes, int n_in,
                              void* d_out, int out_size, void* d_ws, size_t ws_size,
                              hipStream_t stream) {
    const float* x     = (const float*)d_in[0];
    const int*   ei    = (const int*)d_in[1];
    const int*   batch = (const int*)d_in[2];
    const float* w0a = (const float*)d_in[3];  const float* b0a = (const float*)d_in[4];
    const float* w0b = (const float*)d_in[5];  const float* b0b = (const float*)d_in[6];
    const float* w1a = (const float*)d_in[7];  const float* b1a = (const float*)d_in[8];
    const float* w1b = (const float*)d_in[9];  const float* b1b = (const float*)d_in[10];
    const float* w2a = (const float*)d_in[11]; const float* b2a = (const float*)d_in[12];
    const float* w2b = (const float*)d_in[13]; const float* b2b = (const float*)d_in[14];
    const float* bn0g = (const float*)d_in[15]; const float* bn0b = (const float*)d_in[16];
    const float* bn0m = (const float*)d_in[17]; const float* bn0v = (const float*)d_in[18];
    const float* bn1g = (const float*)d_in[19]; const float* bn1b = (const float*)d_in[20];
    const float* bn1m = (const float*)d_in[21]; const float* bn1v = (const float*)d_in[22];
    const float* wp1 = (const float*)d_in[23]; const float* bp1 = (const float*)d_in[24];
    const float* wp2 = (const float*)d_in[25]; const float* bp2 = (const float*)d_in[26];
    float* out = (float*)d_out;

    char* p = (char*)d_ws;
    auto take = [&](size_t bytes) {
        char* r = p;
        p += (bytes + 255) & ~(size_t)255;
        return r;
    };
    int* deg     = (int*)take(NN * sizeof(int));
    int* off     = (int*)take((NN + 1) * sizeof(int));
    int* cursor  = (int*)take(NN * sizeof(int));
    int* partials= (int*)take(128 * sizeof(int));
    int* pref    = (int*)take(128 * sizeof(int));
    int* srcs    = (int*)take(EE * sizeof(int));
    int* gstart  = (int*)take((GG + 1) * sizeof(int));
    ushort* xb   = (ushort*)take((size_t)NN * DD * sizeof(ushort));
    float* bufU  = (float*)take((size_t)NN * DD * sizeof(float));
    ushort* hA   = (ushort*)take((size_t)NN * DD * sizeof(ushort));
    ushort* hB   = (ushort*)take((size_t)NN * DD * sizeof(ushort));
    float* pmean = (float*)take(GG * DD * sizeof(float));
    float* pmax  = (float*)take(GG * DD * sizeof(float));

    // CSR build + graph bounds + x cast
    hipMemsetAsync(deg, 0, NN * sizeof(int), stream);
    hist_kernel<<<(EE + 255) / 256, 256, 0, stream>>>(ei + EE, deg, EE);
    scanA_kernel<<<NB_SCAN, 256, 0, stream>>>(deg, off, partials, NN);
    scanB_kernel<<<1, 128, 0, stream>>>(partials, pref, NB_SCAN);
    scanC_kernel<<<(NN + 255) / 256, 256, 0, stream>>>(off, cursor, pref, deg, NN);
    scatter_kernel<<<(EE + 255) / 256, 256, 0, stream>>>(ei, cursor, srcs, EE);
    bounds_kernel<<<(NN + 255) / 256, 256, 0, stream>>>(batch, gstart, NN);
    cast_kernel<<<(NN * DD / 4 + 255) / 256, 256, 0, stream>>>(x, xb);

    int agg_grid = (NN + 3) / 4;
    int mlp_grid = (NN + 255) / 256;

    // layer 0
    agg_kernel<<<agg_grid, 256, 0, stream>>>(xb, bufU, off, srcs, NN);
    mlp_kernel<true><<<mlp_grid, 256, 0, stream>>>(bufU, hA, w0a, b0a, w0b, b0b,
                                                   bn0g, bn0b, bn0m, bn0v, NN);
    // layer 1
    agg_kernel<<<agg_grid, 256, 0, stream>>>(hA, bufU, off, srcs, NN);
    mlp_kernel<true><<<mlp_grid, 256, 0, stream>>>(bufU, hB, w1a, b1a, w1b, b1b,
                                                   bn1g, bn1b, bn1m, bn1v, NN);
    // layer 2
    agg_kernel<<<agg_grid, 256, 0, stream>>>(hB, bufU, off, srcs, NN);
    mlp_kernel<false><<<mlp_grid, 256, 0, stream>>>(bufU, hA, w2a, b2a, w2b, b2b,
                                                    nullptr, nullptr, nullptr, nullptr, NN);

    // pooling (no atomics) + head
    pool_kernel<<<GG, 256, 0, stream>>>(hA, gstart, pmean, pmax);
    head_kernel<<<GG, 64, 0, stream>>>(pmean, pmax, wp1, bp1, wp2, bp2, out);
}